// Round 2
// baseline (852.655 us; speedup 1.0000x reference)
//
#include <hip/hip_runtime.h>
#include <math.h>

#define NTOK 2048          // BN = B*S
#define HDIM 768           // H
#define NHEAD 12
#define HD 64
#define NVEC (NTOK * NHEAD)   // 24576 head-vectors of length 64

// ---------------------------------------------------------------------------
// Projection: C = hs @ W^T + b for W in {Wq, Wv}.  C[i][j] = sum_k hs[i,k]*W[j,k]
// Both operands are contiguous along k -> no LDS transpose needed.
// grid (HDIM/64, NTOK/64, 2), block 256, thread tile 4x4.
// LDS pitch 36 floats = 144 B (16B-aligned rows -> ds_read_b128 legal;
// +4 shift keeps fragment reads <=2-way banked).
// ---------------------------------------------------------------------------
__global__ __launch_bounds__(256) void proj_kernel(
    const float* __restrict__ hs,
    const float* __restrict__ Wq, const float* __restrict__ bq,
    const float* __restrict__ Wv, const float* __restrict__ bv,
    float* __restrict__ qout, float* __restrict__ vout)
{
    constexpr int BM = 64, BN = 64, BK = 32, PAD = 4;
    __shared__ float As[BM][BK + PAD];
    __shared__ float Ws[BN][BK + PAD];

    const float* W  = blockIdx.z ? Wv : Wq;
    const float* bb = blockIdx.z ? bv : bq;
    float* out      = blockIdx.z ? vout : qout;

    const int tid  = threadIdx.x;
    const int tx   = tid & 15;     // output col group (4 consecutive cols)
    const int ty   = tid >> 4;     // output row group (4 consecutive rows)
    const int row0 = blockIdx.y * BM;
    const int col0 = blockIdx.x * BN;

    float acc[4][4] = {};

    for (int k0 = 0; k0 < HDIM; k0 += BK) {
        #pragma unroll
        for (int p = 0; p < 2; ++p) {          // 64x32 floats / 256 thr = 2 float4 each
            int f = tid + p * 256;
            int r = f >> 3;                    // 0..63
            int c = (f & 7) * 4;               // 0..28
            float4 a = *(const float4*)(hs + (size_t)(row0 + r) * HDIM + k0 + c);
            *(float4*)&As[r][c] = a;
            float4 w = *(const float4*)(W + (size_t)(col0 + r) * HDIM + k0 + c);
            *(float4*)&Ws[r][c] = w;
        }
        __syncthreads();
        #pragma unroll
        for (int k = 0; k < BK; k += 4) {
            float4 a4[4], b4[4];
            #pragma unroll
            for (int r = 0; r < 4; ++r) a4[r] = *(const float4*)&As[ty * 4 + r][k];
            #pragma unroll
            for (int c = 0; c < 4; ++c) b4[c] = *(const float4*)&Ws[tx * 4 + c][k];
            #pragma unroll
            for (int r = 0; r < 4; ++r)
                #pragma unroll
                for (int c = 0; c < 4; ++c) {
                    acc[r][c] = fmaf(a4[r].x, b4[c].x, acc[r][c]);
                    acc[r][c] = fmaf(a4[r].y, b4[c].y, acc[r][c]);
                    acc[r][c] = fmaf(a4[r].z, b4[c].z, acc[r][c]);
                    acc[r][c] = fmaf(a4[r].w, b4[c].w, acc[r][c]);
                }
        }
        __syncthreads();
    }

    float4 bias = *(const float4*)(bb + col0 + tx * 4);
    #pragma unroll
    for (int r = 0; r < 4; ++r) {
        float4 o;
        o.x = acc[r][0] + bias.x;
        o.y = acc[r][1] + bias.y;
        o.z = acc[r][2] + bias.z;
        o.w = acc[r][3] + bias.w;
        *(float4*)(out + (size_t)(row0 + ty * 4 + r) * HDIM + col0 + tx * 4) = o;
    }
}

// ---------------------------------------------------------------------------
// L2-normalize each 64-element chunk of q in place (torch F.normalize, eps=1e-12)
// and record AA[vi] = sum(y*y) post-normalization (reference computes AA on
// the normalized q).  One wave per chunk.
// ---------------------------------------------------------------------------
__global__ __launch_bounds__(256) void norm_kernel(float* __restrict__ q,
                                                   float* __restrict__ AA)
{
    int gid  = blockIdx.x * 256 + threadIdx.x;
    int vi   = gid >> 6;                 // chunk id, 0..NVEC-1
    int lane = threadIdx.x & 63;
    float x  = q[(size_t)vi * 64 + lane];
    float ss = x * x;
    #pragma unroll
    for (int m = 1; m < 64; m <<= 1) ss += __shfl_xor(ss, m);
    float inv = 1.0f / fmaxf(sqrtf(ss), 1e-12f);
    float y = x * inv;
    q[(size_t)vi * 64 + lane] = y;
    float aa = y * y;
    #pragma unroll
    for (int m = 1; m < 64; m <<= 1) aa += __shfl_xor(aa, m);
    if (lane == 0) AA[vi] = aa;
}

// ---------------------------------------------------------------------------
// L2-distance attention, one head-h / 64-query-row tile per block.
//   Q head h = qn rows [h*2048, h*2048+2048)  (24576x64 flat view)
//   V head h = v_full[:, 64h:64h+64]          (column slice of [2048,768])
//   s[n,m] = (2*Q.K - AA[n] - AA[m]) / 8  in [-0.5, 0]  -> exp is stable,
//   no online-max needed (softmax is shift-invariant).
// block 256 (4 waves), key tiles of 64.  LDS ~70 KB -> 2 blocks/CU.
// Pitch 68 floats = 272 B: 16B-aligned rows (b128 legal), bank shift 4/row.
// ---------------------------------------------------------------------------
__global__ __launch_bounds__(256) void attn_kernel(
    const float* __restrict__ qn,      // [24576, 64] normalized
    const float* __restrict__ vfull,   // [2048, 768]
    const float* __restrict__ AA,      // [24576]
    float* __restrict__ out)           // [24576, 64] flat == [B,S,H] flat
{
    __shared__ float Qs[64][68];
    __shared__ float Ks[64][68];
    __shared__ float Vs[64][68];
    __shared__ float Ps[64][68];
    __shared__ float lsum[64];
    __shared__ float aam[64];

    const int h   = blockIdx.y;
    const int n0  = blockIdx.x * 64;
    const int tid = threadIdx.x;
    const int tx  = tid & 15;
    const int ty  = tid >> 4;

    const float* qbase = qn + ((size_t)h * NTOK + n0) * 64;
    #pragma unroll
    for (int p = 0; p < 4; ++p) {              // 64x64 / 256 = 4 float4 each
        int f = tid + p * 256;
        int r = f >> 4, c = (f & 15) * 4;
        *(float4*)&Qs[r][c] = *(const float4*)(qbase + r * 64 + c);
    }
    if (tid < 64) lsum[tid] = 0.0f;

    float aan[4];
    #pragma unroll
    for (int r = 0; r < 4; ++r) aan[r] = AA[(size_t)h * NTOK + n0 + ty * 4 + r];

    float acc[4][4] = {};

    for (int m0 = 0; m0 < NTOK; m0 += 64) {
        const float* kbase = qn + ((size_t)h * NTOK + m0) * 64;
        #pragma unroll
        for (int p = 0; p < 4; ++p) {
            int f = tid + p * 256;
            int r = f >> 4, c = (f & 15) * 4;
            *(float4*)&Ks[r][c] = *(const float4*)(kbase + r * 64 + c);
            *(float4*)&Vs[r][c] =
                *(const float4*)(vfull + (size_t)(m0 + r) * HDIM + h * 64 + c);
        }
        if (tid < 64) aam[tid] = AA[(size_t)h * NTOK + m0 + tid];
        __syncthreads();

        // ---- S = Q.K^T : thread rows ty*4+r, cols tx+16c (spread mapping)
        float s[4][4] = {};
        #pragma unroll
        for (int k = 0; k < 64; k += 4) {
            float4 a4[4], b4[4];
            #pragma unroll
            for (int r = 0; r < 4; ++r) a4[r] = *(const float4*)&Qs[ty * 4 + r][k];
            #pragma unroll
            for (int c = 0; c < 4; ++c) b4[c] = *(const float4*)&Ks[tx + 16 * c][k];
            #pragma unroll
            for (int r = 0; r < 4; ++r)
                #pragma unroll
                for (int c = 0; c < 4; ++c) {
                    s[r][c] = fmaf(a4[r].x, b4[c].x, s[r][c]);
                    s[r][c] = fmaf(a4[r].y, b4[c].y, s[r][c]);
                    s[r][c] = fmaf(a4[r].z, b4[c].z, s[r][c]);
                    s[r][c] = fmaf(a4[r].w, b4[c].w, s[r][c]);
                }
        }

        // ---- p = exp(score), row partial sums
        float p[4][4];
        float psum[4] = {0.f, 0.f, 0.f, 0.f};
        #pragma unroll
        for (int c = 0; c < 4; ++c) {
            float aamc = aam[tx + 16 * c];
            #pragma unroll
            for (int r = 0; r < 4; ++r) {
                float sv = (2.0f * s[r][c] - aan[r] - aamc) * 0.125f;
                float pv = __expf(sv);
                p[r][c] = pv;
                psum[r] += pv;
            }
        }
        // reduce row sums across the 16 tx lanes (low 4 bits of lane id)
        #pragma unroll
        for (int r = 0; r < 4; ++r) {
            float t = psum[r];
            t += __shfl_xor(t, 1);
            t += __shfl_xor(t, 2);
            t += __shfl_xor(t, 4);
            t += __shfl_xor(t, 8);
            if (tx == 0) lsum[ty * 4 + r] += t;   // unique owner per row
        }

        // ---- stage P to LDS for the PV product
        #pragma unroll
        for (int r = 0; r < 4; ++r)
            #pragma unroll
            for (int c = 0; c < 4; ++c)
                Ps[ty * 4 + r][tx + 16 * c] = p[r][c];
        __syncthreads();

        // ---- acc += P @ V : thread rows ty*4+r, d-cols tx*4..tx*4+3
        #pragma unroll
        for (int m0i = 0; m0i < 64; m0i += 4) {
            float pa[4][4];
            #pragma unroll
            for (int r = 0; r < 4; ++r) {
                float4 t = *(const float4*)&Ps[ty * 4 + r][m0i];
                pa[r][0] = t.x; pa[r][1] = t.y; pa[r][2] = t.z; pa[r][3] = t.w;
            }
            #pragma unroll
            for (int mm = 0; mm < 4; ++mm) {
                float4 vb = *(const float4*)&Vs[m0i + mm][tx * 4];
                #pragma unroll
                for (int r = 0; r < 4; ++r) {
                    acc[r][0] = fmaf(pa[r][mm], vb.x, acc[r][0]);
                    acc[r][1] = fmaf(pa[r][mm], vb.y, acc[r][1]);
                    acc[r][2] = fmaf(pa[r][mm], vb.z, acc[r][2]);
                    acc[r][3] = fmaf(pa[r][mm], vb.w, acc[r][3]);
                }
            }
        }
        __syncthreads();   // protect Ks/Vs/Ps before next tile's loads
    }

    #pragma unroll
    for (int r = 0; r < 4; ++r) {
        float inv = 1.0f / lsum[ty * 4 + r];
        float4 o;
        o.x = acc[r][0] * inv; o.y = acc[r][1] * inv;
        o.z = acc[r][2] * inv; o.w = acc[r][3] * inv;
        *(float4*)(out + ((size_t)h * NTOK + n0 + ty * 4 + r) * 64 + tx * 4) = o;
    }
}

// ---------------------------------------------------------------------------
extern "C" void kernel_launch(void* const* d_in, const int* in_sizes, int n_in,
                              void* d_out, int out_size, void* d_ws, size_t ws_size,
                              hipStream_t stream)
{
    const float* hs = (const float*)d_in[0];
    // d_in[1] = g, d_in[2] = attention_mask: feed only dead code -> unused.
    const float* Wq = (const float*)d_in[3];
    const float* bq = (const float*)d_in[4];
    const float* Wv = (const float*)d_in[5];
    const float* bv = (const float*)d_in[6];
    float* out = (float*)d_out;

    float* q_full = (float*)d_ws;                      // [2048*768]
    float* v_full = q_full + (size_t)NTOK * HDIM;      // [2048*768]
    float* AAbuf  = v_full + (size_t)NTOK * HDIM;      // [24576]

    proj_kernel<<<dim3(HDIM / 64, NTOK / 64, 2), 256, 0, stream>>>(
        hs, Wq, bq, Wv, bv, q_full, v_full);
    norm_kernel<<<dim3(NVEC / 4), 256, 0, stream>>>(q_full, AAbuf);
    attn_kernel<<<dim3(NTOK / 64, NHEAD), 256, 0, stream>>>(
        q_full, v_full, AAbuf, out);
}

// Round 3
// 156.401 us; speedup vs baseline: 5.4517x; 5.4517x over previous
//
#include <hip/hip_runtime.h>
#include <math.h>

#define NTOK 2048
#define HDIM 768
#define NHEAD 12
#define NVEC (NTOK * NHEAD)   // 24576 head-vectors of length 64

typedef __attribute__((ext_vector_type(8))) short short8v;   // 8 bf16 (4 VGPR)
typedef __attribute__((ext_vector_type(4))) float float4v;   // MFMA acc

static __device__ __forceinline__ unsigned short f2bf(float x) {
    unsigned u = __float_as_uint(x);
    return (unsigned short)((u + 0x7fffu + ((u >> 16) & 1u)) >> 16);  // RNE
}

static __device__ __forceinline__ void gload_lds16(const void* g, void* lds_uniform) {
    // LDS dest = wave-uniform base + lane*16 (hardware); global src is per-lane.
    __builtin_amdgcn_global_load_lds(
        (const __attribute__((address_space(1))) void*)g,
        (__attribute__((address_space(3))) void*)lds_uniform, 16, 0, 0);
}

// ---------------------------------------------------------------------------
// Projection GEMM (bf16 MFMA): C = hs @ W^T + b, W in {Wq, Wv}.
// grid (12, 32, 2) = 768 blocks, block 128 (2 waves).  Tile 64x64, K-step 32.
// z=0: write q fp32 [token][feature].  z=1: write vT bf16 [feature][token].
// LDS pitch 40 ushort (80 B rows, 16B-aligned): frag reads 2-way banked = free.
// ---------------------------------------------------------------------------
__global__ __launch_bounds__(128) void proj_kernel(
    const float* __restrict__ hs, const float* __restrict__ Wq,
    const float* __restrict__ bq, const float* __restrict__ Wv,
    const float* __restrict__ bv, float* __restrict__ qout,
    unsigned short* __restrict__ vT)
{
    constexpr int PITCH = 40;
    __shared__ unsigned short As[2][64 * PITCH];
    __shared__ unsigned short Bs[2][64 * PITCH];

    const float* W    = blockIdx.z ? Wv : Wq;
    const float* bias = blockIdx.z ? bv : bq;
    const int n0 = blockIdx.x * 64, m0 = blockIdx.y * 64;
    const int tid = threadIdx.x, lane = tid & 63, w = tid >> 6;

    // staging map: thread covers 16 elems: row sr, cols sc..sc+15 of the 64x32 chunk
    const int sr = tid >> 1, sc = (tid & 1) * 16;
    const float* agp = hs + (size_t)(m0 + sr) * HDIM + sc;
    const float* bgp = W  + (size_t)(n0 + sr) * HDIM + sc;

    float4 ga[4], gb[4];
    #pragma unroll
    for (int i = 0; i < 4; ++i) {
        ga[i] = *(const float4*)(agp + i * 4);
        gb[i] = *(const float4*)(bgp + i * 4);
    }

    float4v acc[2][4];
    #pragma unroll
    for (int rs = 0; rs < 2; ++rs)
        #pragma unroll
        for (int t = 0; t < 4; ++t) acc[rs][t] = (float4v){0.f, 0.f, 0.f, 0.f};

    for (int kk = 0; kk < 24; ++kk) {
        const int b = kk & 1;
        union { unsigned short u[16]; short8v v[2]; } pa, pb;
        #pragma unroll
        for (int i = 0; i < 4; ++i) {
            pa.u[i*4+0] = f2bf(ga[i].x); pa.u[i*4+1] = f2bf(ga[i].y);
            pa.u[i*4+2] = f2bf(ga[i].z); pa.u[i*4+3] = f2bf(ga[i].w);
            pb.u[i*4+0] = f2bf(gb[i].x); pb.u[i*4+1] = f2bf(gb[i].y);
            pb.u[i*4+2] = f2bf(gb[i].z); pb.u[i*4+3] = f2bf(gb[i].w);
        }
        *(short8v*)&As[b][sr * PITCH + sc]     = pa.v[0];
        *(short8v*)&As[b][sr * PITCH + sc + 8] = pa.v[1];
        *(short8v*)&Bs[b][sr * PITCH + sc]     = pb.v[0];
        *(short8v*)&Bs[b][sr * PITCH + sc + 8] = pb.v[1];

        if (kk < 23) {                          // prefetch next K-chunk
            agp += 32; bgp += 32;
            #pragma unroll
            for (int i = 0; i < 4; ++i) {
                ga[i] = *(const float4*)(agp + i * 4);
                gb[i] = *(const float4*)(bgp + i * 4);
            }
        }
        __syncthreads();                        // writes to buf b visible

        // wave w owns rows w*32 + rs*16; A row = lane&15, k-grp = lane>>4
        short8v af0 = *(const short8v*)&As[b][(w*32 +      (lane & 15)) * PITCH + ((lane >> 4) << 3)];
        short8v af1 = *(const short8v*)&As[b][(w*32 + 16 + (lane & 15)) * PITCH + ((lane >> 4) << 3)];
        #pragma unroll
        for (int t = 0; t < 4; ++t) {
            short8v bf = *(const short8v*)&Bs[b][((lane & 15) + 16*t) * PITCH + ((lane >> 4) << 3)];
            acc[0][t] = __builtin_amdgcn_mfma_f32_16x16x32_bf16(af0, bf, acc[0][t], 0, 0, 0);
            acc[1][t] = __builtin_amdgcn_mfma_f32_16x16x32_bf16(af1, bf, acc[1][t], 0, 0, 0);
        }
        // no 2nd barrier: next iter writes the OTHER buffer (dbuf), and any wave
        // reaching that write has passed this iter's barrier.
    }

    // epilogue: C row = (lane>>4)*4+reg (token), col = (lane&15)+16t (feature)
    float bcol[4];
    #pragma unroll
    for (int t = 0; t < 4; ++t) bcol[t] = bias[n0 + (lane & 15) + 16*t];

    if (blockIdx.z == 0) {
        #pragma unroll
        for (int rs = 0; rs < 2; ++rs)
            #pragma unroll
            for (int t = 0; t < 4; ++t)
                #pragma unroll
                for (int r = 0; r < 4; ++r) {
                    int m = m0 + w*32 + rs*16 + ((lane >> 4) << 2) + r;
                    qout[(size_t)m * HDIM + n0 + (lane & 15) + 16*t] = acc[rs][t][r] + bcol[t];
                }
    } else {
        // vT[feature][token] bf16; lane's 4 regs = 4 consecutive tokens -> 8B store
        #pragma unroll
        for (int rs = 0; rs < 2; ++rs)
            #pragma unroll
            for (int t = 0; t < 4; ++t) {
                int f = n0 + (lane & 15) + 16*t;
                int mb = m0 + w*32 + rs*16 + ((lane >> 4) << 2);
                union { unsigned short u[4]; unsigned long long q; } pk;
                #pragma unroll
                for (int r = 0; r < 4; ++r) pk.u[r] = f2bf(acc[rs][t][r] + bcol[t]);
                *(unsigned long long*)(vT + (size_t)f * NTOK + mb) = pk.q;
            }
    }
}

// ---------------------------------------------------------------------------
// L2-normalize each 64-chunk of q (torch F.normalize, eps=1e-12), emit bf16.
// Post-normalization AA == 1 exactly -> softmax needs no AA terms at all.
// ---------------------------------------------------------------------------
__global__ __launch_bounds__(256) void norm_kernel(const float* __restrict__ q,
                                                   unsigned short* __restrict__ qbf)
{
    int gid  = blockIdx.x * 256 + threadIdx.x;
    int vi   = gid >> 6;
    int lane = threadIdx.x & 63;
    float x  = q[(size_t)vi * 64 + lane];
    float ss = x * x;
    #pragma unroll
    for (int m = 1; m < 64; m <<= 1) ss += __shfl_xor(ss, m);
    float inv = 1.0f / fmaxf(sqrtf(ss), 1e-12f);
    qbf[(size_t)vi * 64 + lane] = f2bf(x * inv);
}

// ---------------------------------------------------------------------------
// MFMA flash attention.  score = (2*q.k - 2)/8 -> softmax == exp(q.k/4) norm'd.
// grid 768 (= 64 q-tiles x 12 heads, XCD-swizzled), block 128 = 2 waves.
// Wave owns 16 q-rows (Q frags persistent in VGPR).  K-tile = 64 keys.
// K/V double-buffered via global_load_lds w/ pre-swizzled source (T2 swizzle
// byte ^= (row&7)<<4); one barrier per tile.  P via wave-private swizzled LDS.
// LDS 36 KB -> 4 blocks/CU; grid 3 blocks/CU => fully co-resident, no tail.
// ---------------------------------------------------------------------------
__global__ __launch_bounds__(128) void attn_kernel(
    const unsigned short* __restrict__ qbf,   // [24576][64] bf16 normalized
    const unsigned short* __restrict__ vT,    // [768][2048] bf16
    float* __restrict__ out)                  // [24576][64] f32
{
    __shared__ unsigned short Ksb[2][64 * 64];
    __shared__ unsigned short Vsb[2][64 * 64];
    __shared__ unsigned short Psb[2][16 * 64];   // [wave][16 q-rows][64 keys]

    const int bid = blockIdx.x;
    const int swz = (bid & 7) * 96 + (bid >> 3);   // bijective: 768 % 8 == 0
    const int h = swz >> 6, n0 = (swz & 63) * 32;
    const int tid = threadIdx.x, lane = tid & 63, w = tid >> 6;

    // persistent Q fragments: A row = lane&15, k-grp = lane>>4
    const unsigned short* qrow =
        qbf + ((size_t)h * NTOK + n0 + w * 16 + (lane & 15)) * 64;
    short8v qa[2];
    qa[0] = *(const short8v*)(qrow + ((lane >> 4) << 3));
    qa[1] = *(const short8v*)(qrow + 32 + ((lane >> 4) << 3));

    const unsigned short* kh = qbf + (size_t)h * NTOK * 64;  // head's K rows
    const unsigned short* vh = vT + (size_t)h * 64 * NTOK;   // head's vT rows

#define STAGE(buf, m0v)                                                        \
    {                                                                          \
        const unsigned short* kbase = kh + (size_t)(m0v) * 64;                 \
        const unsigned short* vbase = vh + (m0v);                              \
        _Pragma("unroll")                                                      \
        for (int i = 0; i < 4; ++i) {                                          \
            int ci = ((w * 4 + i) << 6) + lane;                                \
            int r = ci >> 3, c8 = ci & 7;                                      \
            int cs = (c8 ^ (r & 7)) << 3;                                      \
            gload_lds16(kbase + (r << 6) + cs,                                 \
                        (char*)&Ksb[buf][0] + ((w * 4 + i) << 10));            \
            gload_lds16(vbase + r * NTOK + cs,                                 \
                        (char*)&Vsb[buf][0] + ((w * 4 + i) << 10));            \
        }                                                                      \
    }

    float4v acc[4];
    #pragma unroll
    for (int t = 0; t < 4; ++t) acc[t] = (float4v){0.f, 0.f, 0.f, 0.f};
    float lsum[4] = {0.f, 0.f, 0.f, 0.f};

    STAGE(0, 0);
    __syncthreads();
    int cur = 0;

    for (int mt = 0; mt < 32; ++mt) {
        if (mt < 31) STAGE(cur ^ 1, (mt + 1) * 64);   // prefetch next tile

        // ---- S = Q.K^T  (16 q-rows x 64 keys per wave)
        float4v S[4];
        #pragma unroll
        for (int t = 0; t < 4; ++t) {
            S[t] = (float4v){0.f, 0.f, 0.f, 0.f};
            #pragma unroll
            for (int kk = 0; kk < 2; ++kk) {
                int row = (lane & 15) + (t << 4);
                int off = ((row << 7) + (kk << 6) + ((lane >> 4) << 4)) ^ ((row & 7) << 4);
                short8v kf = *(const short8v*)((const char*)&Ksb[cur][0] + off);
                S[t] = __builtin_amdgcn_mfma_f32_16x16x32_bf16(qa[kk], kf, S[t], 0, 0, 0);
            }
        }

        // ---- p = exp(s/4); row sums; stage P (bf16, swizzled, wave-private)
        float p[4][4];
        #pragma unroll
        for (int t = 0; t < 4; ++t)
            #pragma unroll
            for (int r = 0; r < 4; ++r)
                p[t][r] = __expf(S[t][r] * 0.25f);

        #pragma unroll
        for (int r = 0; r < 4; ++r) {
            float ss = p[0][r] + p[1][r] + p[2][r] + p[3][r];
            ss += __shfl_xor(ss, 1);
            ss += __shfl_xor(ss, 2);
            ss += __shfl_xor(ss, 4);
            ss += __shfl_xor(ss, 8);
            lsum[r] += ss;                 // row (lane>>4)*4+r of this wave
        }

        #pragma unroll
        for (int t = 0; t < 4; ++t)
            #pragma unroll
            for (int r = 0; r < 4; ++r) {
                int pr = ((lane >> 4) << 2) + r, pc = (lane & 15) + (t << 4);
                int off = ((pr << 7) + (pc << 1)) ^ ((pr & 7) << 4);
                *(unsigned short*)((char*)&Psb[w][0] + off) = f2bf(p[t][r]);
            }

        // ---- acc += P @ V  (A=P: row=lane&15; B=V from vT rows = d)
        #pragma unroll
        for (int kk = 0; kk < 2; ++kk) {
            int prr = lane & 15;
            int poff = ((prr << 7) + (kk << 6) + ((lane >> 4) << 4)) ^ ((prr & 7) << 4);
            short8v pf = *(const short8v*)((const char*)&Psb[w][0] + poff);
            #pragma unroll
            for (int t = 0; t < 4; ++t) {
                int vr = (lane & 15) + (t << 4);
                int voff = ((vr << 7) + (kk << 6) + ((lane >> 4) << 4)) ^ ((vr & 7) << 4);
                short8v vf = *(const short8v*)((const char*)&Vsb[cur][0] + voff);
                acc[t] = __builtin_amdgcn_mfma_f32_16x16x32_bf16(pf, vf, acc[t], 0, 0, 0);
            }
        }

        __syncthreads();    // drains prefetch DMA (all waves) + frees cur buffer
        cur ^= 1;
    }
#undef STAGE

    float inv[4];
    #pragma unroll
    for (int r = 0; r < 4; ++r) inv[r] = 1.0f / lsum[r];
    #pragma unroll
    for (int t = 0; t < 4; ++t)
        #pragma unroll
        for (int r = 0; r < 4; ++r) {
            int n = n0 + w * 16 + ((lane >> 4) << 2) + r;
            int d = (lane & 15) + (t << 4);
            out[((size_t)h * NTOK + n) * 64 + d] = acc[t][r] * inv[r];
        }
}

// ---------------------------------------------------------------------------
extern "C" void kernel_launch(void* const* d_in, const int* in_sizes, int n_in,
                              void* d_out, int out_size, void* d_ws, size_t ws_size,
                              hipStream_t stream)
{
    const float* hs = (const float*)d_in[0];
    // d_in[1] = g, d_in[2] = attention_mask: feed only dead code -> unused.
    const float* Wq = (const float*)d_in[3];
    const float* bq = (const float*)d_in[4];
    const float* Wv = (const float*)d_in[5];
    const float* bv = (const float*)d_in[6];
    float* out = (float*)d_out;

    float*          q_full = (float*)d_ws;                         // [2048*768] f32
    unsigned short* qbf    = (unsigned short*)(q_full + (size_t)NTOK * HDIM);  // [24576*64] bf16
    unsigned short* vT     = qbf + (size_t)NVEC * 64;              // [768*2048] bf16

    proj_kernel<<<dim3(HDIM / 64, NTOK / 64, 2), 128, 0, stream>>>(
        hs, Wq, bq, Wv, bv, q_full, vT);
    norm_kernel<<<dim3(NVEC * 64 / 256), 256, 0, stream>>>(q_full, qbf);
    attn_kernel<<<dim3(768), 128, 0, stream>>>(qbf, vT, out);
}